// Round 8
// baseline (92.588 us; speedup 1.0000x reference)
//
#include <hip/hip_runtime.h>
#include <hip/hip_bf16.h>

// MoE fused kernel for MI355X (gfx950) — R8: dual-pipe weight ingress.
// out[t,o] = sum_e w[t,e] * (relu(x[t]@W1[e]^T) @ W2[e]^T),
// w = softmax_e(mask( relu(x@sg1^T)@(gate_w@sg_w2)^T + x@gate_w^T ))
//
// Structure: 512 blocks x 256 thr (4 waves) = 2 blocks/CU, 2 waves/SIMD.
// 32 tokens/wave. Per 32-hid chunk: W1 fragments stream via global_load_lds
// into a double-buffered LDS chunk (LDS pipe); W2 fragments stream via
// direct global loads into register double-buffers (vmem/L1 pipe). Both
// ingress pipes sit under the ~1242-cyc/SIMD MFMA shadow; 2 blocks/CU give
// two independent barrier domains (chunk barriers overlap across blocks);
// 2 waves/SIMD hide pack-VALU under the other wave's MFMA.
// Expert math (verified R5-R7): G1 swapped mfma(W1,X) -> D[hid][token];
// W2 prep-packed (chunk-major, permuted k-order) so relu*w + bf16-pack of
// the G1 accumulator IS a legal G2 B-fragment; G2 swapped -> D[out][token]
// -> direct coalesced f32x4 stores.

typedef float f32x4 __attribute__((ext_vector_type(4)));
typedef short bf16x8 __attribute__((ext_vector_type(8)));

static __device__ __forceinline__ short f2bs(float f) {
  union { __hip_bfloat16 b; short s; } u;
  u.b = __float2bfloat16(f);
  return u.s;
}

static __device__ __forceinline__ unsigned pk2(float lo, float hi) {
  union { __hip_bfloat162 b; unsigned u; } t;
  t.b = __float22bfloat162_rn(make_float2(lo, hi));
  return t.u;
}

// ws layout (shorts):
//  [0,262144)       W1p : (c*8 + i)*512 + lane*8 + j, c=e*8+ks, i=n*4+kx
//                         = W1[e][ks*32+n*16+l15][kx*32+lg*8+j]
//  [262144,524288)  W2p : (c*8 + oi)*512 + lane*8 + j   (chunk-major)
//                         = W2[e][oi*16+l15][ks*32 + perm(lg,j)]
//                           perm(lg,j) = j<4 ? lg*4+j : 16+lg*4+(j-4)
//  [524288,526336)  sg1p: k*512 + lane*8 + j = sg_w1[l15][k*32+lg*8+j]
//  [526336,528384)  gwp : k*512 + lane*8 + j = l15<8 ? gate_w[l15][...] : 0
//  [528384,528896)  gcp : lane*8 + j = (l15<8 && lg*8+j<16) ? gc[l15][lg*8+j] : 0
//                         gc = gate_w @ sg_w2  [8,16]

__global__ void prep_kernel(const float* __restrict__ sg_w1,
                            const float* __restrict__ sg_w2,
                            const float* __restrict__ gate_w,
                            const float* __restrict__ exp_w1,
                            const float* __restrict__ exp_w2,
                            short* __restrict__ ws_s) {
  int idx = blockIdx.x * 256 + threadIdx.x;
  if (idx < 262144) {
    int e = idx >> 15, rem = idx & 32767;
    int frag = rem >> 9, lane = (rem >> 3) & 63, j = rem & 7;
    int hid = (frag >> 2) * 16 + (lane & 15);
    int k   = (frag & 3) * 32 + (lane >> 4) * 8 + j;
    ws_s[idx] = f2bs(exp_w1[(e * 256 + hid) * 128 + k]);
  } else if (idx < 524288) {
    int i2 = idx - 262144;
    int e = i2 >> 15, rem = i2 & 32767;
    int frag = rem >> 9, lane = (rem >> 3) & 63, j = rem & 7;
    int lg = lane >> 4, l15 = lane & 15;
    int ks = frag >> 3;          // chunk-major: frag = ks*8 + oi
    int oi = frag & 7;
    int o  = oi * 16 + l15;
    int h  = ks * 32 + (j < 4 ? lg * 4 + j : 16 + lg * 4 + (j - 4));
    ws_s[idx] = f2bs(exp_w2[(e * 128 + o) * 256 + h]);
  } else if (idx < 526336) {
    int i3 = idx - 524288;
    int k = i3 >> 9, lane = (i3 >> 3) & 63, j = i3 & 7;
    int lg = lane >> 4, l15 = lane & 15;
    ws_s[idx] = f2bs(sg_w1[l15 * 128 + k * 32 + lg * 8 + j]);
  } else if (idx < 528384) {
    int i4 = idx - 526336;
    int k = i4 >> 9, lane = (i4 >> 3) & 63, j = i4 & 7;
    int lg = lane >> 4, l15 = lane & 15;
    ws_s[idx] = (l15 < 8) ? f2bs(gate_w[l15 * 128 + k * 32 + lg * 8 + j]) : (short)0;
  } else if (idx < 528896) {
    int i5 = idx - 528384;
    int lane = (i5 >> 3) & 63, j = i5 & 7;
    int lg = lane >> 4, l15 = lane & 15;
    int kk = lg * 8 + j;
    if (l15 < 8 && kk < 16) {
      float acc = 0.f;
      for (int d = 0; d < 128; ++d) acc += gate_w[l15 * 128 + d] * sg_w2[d * 16 + kk];
      ws_s[idx] = f2bs(acc);
    } else {
      ws_s[idx] = 0;
    }
  }
}

__global__ __launch_bounds__(256, 2) void moe_kernel(
    const float* __restrict__ x, const int* __restrict__ active,
    const short* __restrict__ ws_s, float* __restrict__ out) {
  __shared__ __align__(16) short Abuf[2][4096];  // W1 chunk dbuf (8KB each)
  __shared__ short Ul[4][1280];  // per-wave [32][40] bf16 U tile (cols 16+ zero)

  const short* W1p  = ws_s;
  const short* W2p  = ws_s + 262144;
  const short* sg1p = ws_s + 524288;
  const short* gwp  = ws_s + 526336;
  const short* gcp  = ws_s + 528384;

  const int tid  = threadIdx.x;
  const int lane = tid & 63;
  const int wid  = tid >> 6;     // 0..3
  const int l15  = lane & 15;
  const int lg   = lane >> 4;    // 0..3
  const int tokw = blockIdx.x * 128 + wid * 32;

  // stage W1 chunk c into Abuf[buf]: wave wid copies frags 2*wid, 2*wid+1
  auto stageA = [&](int buf, int c) {
#pragma unroll
    for (int t = 0; t < 2; ++t) {
      int i = wid * 2 + t;
      const short* s = W1p + ((size_t)c * 8 + i) * 512 + lane * 8;
      __builtin_amdgcn_global_load_lds(
          (const __attribute__((address_space(1))) void*)s,
          (__attribute__((address_space(3))) void*)(&Abuf[buf][i * 512]),
          16, 0, 0);
    }
  };
  // load W2 chunk c into register buffer (vmem pipe, L1-served)
  auto loadB = [&](bf16x8 (&B)[8], int c) {
    const short* p = W2p + (size_t)c * 4096 + lane * 8;
#pragma unroll
    for (int oi = 0; oi < 8; ++oi)
      B[oi] = *(const bf16x8*)(p + oi * 512);
  };

  stageA(0, 0);  // prologue; drains at first barrier

  short* Ulw = &Ul[wid][0];
  for (int i = lane; i < 640; i += 64) ((int*)Ulw)[i] = 0;

  // ---- X fragments: lane holds row=token(l15 + m*16), k=lg*8+j ----
  bf16x8 xf[2][4];
  {
    int trow = tokw + l15;
#pragma unroll
    for (int m = 0; m < 2; ++m) {
      const float* xr = x + (size_t)(trow + m * 16) * 128;
#pragma unroll
      for (int k = 0; k < 4; ++k) {
        int c = k * 32 + lg * 8;
        float4 a = *(const float4*)(xr + c);
        float4 b = *(const float4*)(xr + c + 4);
        bf16x8 v;
        v[0] = f2bs(a.x); v[1] = f2bs(a.y); v[2] = f2bs(a.z); v[3] = f2bs(a.w);
        v[4] = f2bs(b.x); v[5] = f2bs(b.y); v[6] = f2bs(b.z); v[7] = f2bs(b.w);
        xf[m][k] = v;
      }
    }
  }
  __syncthreads();  // zero-init + stage(0) drained

  // ---- gate (verified R5 structure) ----
  f32x4 wreg[2];
  {
    bf16x8 sgf[4], gwf[4];
#pragma unroll
    for (int k = 0; k < 4; ++k) {
      sgf[k] = *(const bf16x8*)(sg1p + k * 512 + lane * 8);
      gwf[k] = *(const bf16x8*)(gwp  + k * 512 + lane * 8);
    }
#pragma unroll
    for (int m = 0; m < 2; ++m) {
      f32x4 acc = {0.f, 0.f, 0.f, 0.f};
#pragma unroll
      for (int k = 0; k < 4; ++k)
        acc = __builtin_amdgcn_mfma_f32_16x16x32_bf16(xf[m][k], sgf[k], acc, 0, 0, 0);
#pragma unroll
      for (int r = 0; r < 4; ++r)
        Ulw[(m * 16 + lg * 4 + r) * 40 + l15] = f2bs(fmaxf(acc[r], 0.f));
    }
    f32x4 sc[2];
#pragma unroll
    for (int m = 0; m < 2; ++m) {
      f32x4 acc = {0.f, 0.f, 0.f, 0.f};
#pragma unroll
      for (int k = 0; k < 4; ++k)
        acc = __builtin_amdgcn_mfma_f32_16x16x32_bf16(xf[m][k], gwf[k], acc, 0, 0, 0);
      sc[m] = acc;
    }
    __syncthreads();  // U-writes (rows lg*4+r) visible to uf-reads (rows l15)
    bf16x8 gcf = *(const bf16x8*)(gcp + lane * 8);
#pragma unroll
    for (int m = 0; m < 2; ++m) {
      bf16x8 uf = *(const bf16x8*)(Ulw + (m * 16 + l15) * 40 + lg * 8);
      sc[m] = __builtin_amdgcn_mfma_f32_16x16x32_bf16(uf, gcf, sc[m], 0, 0, 0);
    }
    int b = tokw >> 12;
    float am = (l15 < 8 && active[b * 8 + l15] != 0) ? 0.f : -3.0e38f;
#pragma unroll
    for (int m = 0; m < 2; ++m) {
      f32x4 w4;
#pragma unroll
      for (int r = 0; r < 4; ++r) {
        float s = sc[m][r] + am;
        float mx = s;
        mx = fmaxf(mx, __shfl_xor(mx, 1));
        mx = fmaxf(mx, __shfl_xor(mx, 2));
        mx = fmaxf(mx, __shfl_xor(mx, 4));
        float p = __expf(s - mx);
        float su = p;
        su += __shfl_xor(su, 1);
        su += __shfl_xor(su, 2);
        su += __shfl_xor(su, 4);
        w4[r] = p / su;
      }
      wreg[m] = w4;
    }
  }

  // ---- expert loop ----
  f32x4 acc2[2][8];
#pragma unroll
  for (int m = 0; m < 2; ++m)
#pragma unroll
    for (int o = 0; o < 8; ++o)
      acc2[m][o] = {0.f, 0.f, 0.f, 0.f};

  bf16x8 Ba[8], Bb[8];
  loadB(Ba, 0);  // prologue W2 chunk 0

  for (int e = 0; e < 8; ++e) {
    // wv[m] = w[token=l15 (+m*16)][e]; source lane ((l15>>2)<<4)|e, reg l15&3
    float wv[2];
    {
      int srcb = ((l15 >> 2) << 4) | e;
      int rp = l15 & 3;
#pragma unroll
      for (int m = 0; m < 2; ++m) {
        float q0 = __shfl(wreg[m][0], srcb), q1 = __shfl(wreg[m][1], srcb);
        float q2 = __shfl(wreg[m][2], srcb), q3 = __shfl(wreg[m][3], srcb);
        float lo = (rp & 1) ? q1 : q0, hi = (rp & 1) ? q3 : q2;
        wv[m] = (rp & 2) ? hi : lo;
      }
    }

    auto chunk_body = [&](bf16x8 (&Bcur)[8], bf16x8 (&Bnext)[8], int bufA, int c) {
      if (c < 63) {
        stageA(bufA ^ 1, c + 1);   // W1(c+1) -> other LDS buffer (vmem->LDS)
        loadB(Bnext, c + 1);       // W2(c+1) -> other reg buffer (vmem)
      }
      // W1 fragments for chunk c from LDS (conflict-free ds_read_b128)
      bf16x8 Af[8];
#pragma unroll
      for (int i = 0; i < 8; ++i)
        Af[i] = *(const bf16x8*)(&Abuf[bufA][i * 512 + lane * 8]);

      // G1: D[hid][token] for this 32-hid chunk (2 hid-tiles x K=128)
      f32x4 a1[2][2];
#pragma unroll
      for (int m = 0; m < 2; ++m)
#pragma unroll
        for (int n = 0; n < 2; ++n) {
          f32x4 acc = {0.f, 0.f, 0.f, 0.f};
#pragma unroll
          for (int kx = 0; kx < 4; ++kx)
            acc = __builtin_amdgcn_mfma_f32_16x16x32_bf16(Af[n * 4 + kx], xf[m][kx], acc, 0, 0, 0);
          a1[m][n] = acc;
        }
      // pack: relu * wv, f32 -> packed bf16 (v_cvt_pk_bf16_f32)
      bf16x8 hB[2];
#pragma unroll
      for (int m = 0; m < 2; ++m) {
        float s = wv[m];
        union { unsigned u[4]; bf16x8 v; } hb;
        hb.u[0] = pk2(fmaxf(a1[m][0][0], 0.f) * s, fmaxf(a1[m][0][1], 0.f) * s);
        hb.u[1] = pk2(fmaxf(a1[m][0][2], 0.f) * s, fmaxf(a1[m][0][3], 0.f) * s);
        hb.u[2] = pk2(fmaxf(a1[m][1][0], 0.f) * s, fmaxf(a1[m][1][1], 0.f) * s);
        hb.u[3] = pk2(fmaxf(a1[m][1][2], 0.f) * s, fmaxf(a1[m][1][3], 0.f) * s);
        hB[m] = hb.v;
      }
      // G2: acc2[m][o] += mfma(W2frag[o], hB[m])  (D[out][token])
#pragma unroll
      for (int o = 0; o < 8; ++o)
#pragma unroll
        for (int m = 0; m < 2; ++m)
          acc2[m][o] = __builtin_amdgcn_mfma_f32_16x16x32_bf16(Bcur[o], hB[m], acc2[m][o], 0, 0, 0);

      __syncthreads();  // A(c+1) staged (drained under compute); buffer handoff
    };

#pragma unroll
    for (int kk = 0; kk < 4; ++kk) {
      int c0 = e * 8 + 2 * kk;
      chunk_body(Ba, Bb, 0, c0);      // even chunk: A in buf0, W2 in Ba
      chunk_body(Bb, Ba, 1, c0 + 1);  // odd  chunk: A in buf1, W2 in Bb
    }
  }

  // ---- direct stores: lane holds out = o*16+lg*4..+3, token = l15 (+m*16) ----
#pragma unroll
  for (int m = 0; m < 2; ++m)
#pragma unroll
    for (int o = 0; o < 8; ++o)
      *(f32x4*)(out + (size_t)(tokw + m * 16 + l15) * 128 + o * 16 + lg * 4) = acc2[m][o];

  if (blockIdx.x == 0 && tid == 0) out[8388608] = 0.0f;  // aux_loss
}

extern "C" void kernel_launch(void* const* d_in, const int* in_sizes, int n_in,
                              void* d_out, int out_size, void* d_ws, size_t ws_size,
                              hipStream_t stream) {
  const float* x      = (const float*)d_in[0];
  const int*   act    = (const int*)d_in[1];
  const float* sg_w1  = (const float*)d_in[2];
  const float* sg_w2  = (const float*)d_in[3];
  const float* gate_w = (const float*)d_in[4];
  const float* exp_w1 = (const float*)d_in[5];
  const float* exp_w2 = (const float*)d_in[6];
  short* ws_s = (short*)d_ws;
  float* out = (float*)d_out;

  prep_kernel<<<2066, 256, 0, stream>>>(sg_w1, sg_w2, gate_w, exp_w1, exp_w2, ws_s);
  moe_kernel<<<512, 256, 0, stream>>>(x, act, ws_s, out);
}

// Round 9
// 82.474 us; speedup vs baseline: 1.1226x; 1.1226x over previous
//
#include <hip/hip_runtime.h>
#include <hip/hip_bf16.h>

// MoE fused kernel for MI355X (gfx950) — R9: counted-vmcnt ring pipeline.
// out[t,o] = sum_e w[t,e] * (relu(x[t]@W1[e]^T) @ W2[e]^T),
// w = softmax_e(mask( relu(x@sg1^T)@(gate_w@sg_w2)^T + x@gate_w^T ))
//
// 512 blocks x 256 thr (4 waves) = 2 blocks/CU, 2 waves/SIMD, 32 tok/wave.
// All 16 weight fragments per 32-hid chunk staged via global_load_lds into a
// 4-deep LDS ring, depth-2 prefetch. Per chunk: [issue stage(c+2)] ->
// [s_waitcnt vmcnt(8) : own chunk-c loads landed] -> [raw s_barrier] ->
// [ds_read c] -> [G1/pack/G2]. NO vmcnt(0) drain in the main loop (T3/T4).
// Hazards: RAW = per-wave vmcnt before barrier; WAR = writers at ring
// distance 2-3 from any concurrent reader (mod 4); WAW = two barriers apart.
// Expert math (verified R5-R8): G1 swapped mfma(W1,X) -> D[hid][token];
// W2 prep-packed (chunk-major, permuted k-order) so relu*w + bf16-pack of
// the G1 accumulator IS a legal G2 B-fragment; G2 swapped -> D[out][token]
// -> direct coalesced f32x4 stores.

typedef float f32x4 __attribute__((ext_vector_type(4)));
typedef short bf16x8 __attribute__((ext_vector_type(8)));

static __device__ __forceinline__ short f2bs(float f) {
  union { __hip_bfloat16 b; short s; } u;
  u.b = __float2bfloat16(f);
  return u.s;
}

static __device__ __forceinline__ unsigned pk2(float lo, float hi) {
  union { __hip_bfloat162 b; unsigned u; } t;
  t.b = __float22bfloat162_rn(make_float2(lo, hi));
  return t.u;
}

// ws layout (shorts):
//  [0,262144)       W1p : (c*8 + i)*512 + lane*8 + j, c=e*8+ks, i=n*4+kx
//                         = W1[e][ks*32+n*16+l15][kx*32+lg*8+j]
//  [262144,524288)  W2p : (c*8 + oi)*512 + lane*8 + j   (chunk-major)
//                         = W2[e][oi*16+l15][ks*32 + perm(lg,j)]
//                           perm(lg,j) = j<4 ? lg*4+j : 16+lg*4+(j-4)
//  [524288,526336)  sg1p: k*512 + lane*8 + j = sg_w1[l15][k*32+lg*8+j]
//  [526336,528384)  gwp : k*512 + lane*8 + j = l15<8 ? gate_w[l15][...] : 0
//  [528384,528896)  gcp : lane*8 + j = (l15<8 && lg*8+j<16) ? gc[l15][lg*8+j] : 0
//                         gc = gate_w @ sg_w2  [8,16]

__global__ void prep_kernel(const float* __restrict__ sg_w1,
                            const float* __restrict__ sg_w2,
                            const float* __restrict__ gate_w,
                            const float* __restrict__ exp_w1,
                            const float* __restrict__ exp_w2,
                            short* __restrict__ ws_s) {
  int idx = blockIdx.x * 256 + threadIdx.x;
  if (idx < 262144) {
    int e = idx >> 15, rem = idx & 32767;
    int frag = rem >> 9, lane = (rem >> 3) & 63, j = rem & 7;
    int hid = (frag >> 2) * 16 + (lane & 15);
    int k   = (frag & 3) * 32 + (lane >> 4) * 8 + j;
    ws_s[idx] = f2bs(exp_w1[(e * 256 + hid) * 128 + k]);
  } else if (idx < 524288) {
    int i2 = idx - 262144;
    int e = i2 >> 15, rem = i2 & 32767;
    int frag = rem >> 9, lane = (rem >> 3) & 63, j = rem & 7;
    int lg = lane >> 4, l15 = lane & 15;
    int ks = frag >> 3;          // chunk-major: frag = ks*8 + oi
    int oi = frag & 7;
    int o  = oi * 16 + l15;
    int h  = ks * 32 + (j < 4 ? lg * 4 + j : 16 + lg * 4 + (j - 4));
    ws_s[idx] = f2bs(exp_w2[(e * 128 + o) * 256 + h]);
  } else if (idx < 526336) {
    int i3 = idx - 524288;
    int k = i3 >> 9, lane = (i3 >> 3) & 63, j = i3 & 7;
    int lg = lane >> 4, l15 = lane & 15;
    ws_s[idx] = f2bs(sg_w1[l15 * 128 + k * 32 + lg * 8 + j]);
  } else if (idx < 528384) {
    int i4 = idx - 526336;
    int k = i4 >> 9, lane = (i4 >> 3) & 63, j = i4 & 7;
    int lg = lane >> 4, l15 = lane & 15;
    ws_s[idx] = (l15 < 8) ? f2bs(gate_w[l15 * 128 + k * 32 + lg * 8 + j]) : (short)0;
  } else if (idx < 528896) {
    int i5 = idx - 528384;
    int lane = (i5 >> 3) & 63, j = i5 & 7;
    int lg = lane >> 4, l15 = lane & 15;
    int kk = lg * 8 + j;
    if (l15 < 8 && kk < 16) {
      float acc = 0.f;
      for (int d = 0; d < 128; ++d) acc += gate_w[l15 * 128 + d] * sg_w2[d * 16 + kk];
      ws_s[idx] = f2bs(acc);
    } else {
      ws_s[idx] = 0;
    }
  }
}

__global__ __launch_bounds__(256, 2) void moe_kernel(
    const float* __restrict__ x, const int* __restrict__ active,
    const short* __restrict__ ws_s, float* __restrict__ out) {
  // 4-deep ring of 16KB weight chunks (slots 0-7 = W1 frags, 8-15 = W2 frags)
  __shared__ __align__(16) short Wring[4][8192];
  __shared__ short Ul[4][1280];  // per-wave [32][40] bf16 U tile (cols 16+ zero)

  const short* W1p  = ws_s;
  const short* W2p  = ws_s + 262144;
  const short* sg1p = ws_s + 524288;
  const short* gwp  = ws_s + 526336;
  const short* gcp  = ws_s + 528384;

  const int tid  = threadIdx.x;
  const int lane = tid & 63;
  const int wid  = tid >> 6;     // 0..3
  const int l15  = lane & 15;
  const int lg   = lane >> 4;    // 0..3
  const int tokw = blockIdx.x * 128 + wid * 32;

  // stage chunk c into ring[c&3]: wave wid copies frags 4*wid..4*wid+3
  // (frag f<8 = W1 frag f; f>=8 = W2 frag f-8). 16B/lane, lane-linear dest.
  auto stage = [&](int c) {
    int buf = c & 3;
#pragma unroll
    for (int t = 0; t < 4; ++t) {
      int f = wid * 4 + t;
      const short* s = (f < 8)
          ? (W1p + ((size_t)c * 8 + f) * 512 + lane * 8)
          : (W2p + ((size_t)c * 8 + (f - 8)) * 512 + lane * 8);
      __builtin_amdgcn_global_load_lds(
          (const __attribute__((address_space(1))) void*)s,
          (__attribute__((address_space(3))) void*)(&Wring[buf][f * 512]),
          16, 0, 0);
    }
  };
  auto waitv = [&](int n) {
    if (n == 8)      asm volatile("s_waitcnt vmcnt(8)" ::: "memory");
    else if (n == 4) asm volatile("s_waitcnt vmcnt(4)" ::: "memory");
    else             asm volatile("s_waitcnt vmcnt(0)" ::: "memory");
    __builtin_amdgcn_sched_barrier(0);
  };

  stage(0);  // depth-2 prologue
  stage(1);

  short* Ulw = &Ul[wid][0];
  for (int i = lane; i < 640; i += 64) ((int*)Ulw)[i] = 0;

  // ---- X fragments: lane holds row=token(l15 + m*16), k=lg*8+j ----
  bf16x8 xf[2][4];
  {
    int trow = tokw + l15;
#pragma unroll
    for (int m = 0; m < 2; ++m) {
      const float* xr = x + (size_t)(trow + m * 16) * 128;
#pragma unroll
      for (int k = 0; k < 4; ++k) {
        int c = k * 32 + lg * 8;
        float4 a = *(const float4*)(xr + c);
        float4 b = *(const float4*)(xr + c + 4);
        bf16x8 v;
        v[0] = f2bs(a.x); v[1] = f2bs(a.y); v[2] = f2bs(a.z); v[3] = f2bs(a.w);
        v[4] = f2bs(b.x); v[5] = f2bs(b.y); v[6] = f2bs(b.z); v[7] = f2bs(b.w);
        xf[m][k] = v;
      }
    }
  }
  __syncthreads();  // zero-init visible (full drain once here is fine)

  // ---- gate (verified R5 structure) ----
  f32x4 wreg[2];
  {
    bf16x8 sgf[4], gwf[4];
#pragma unroll
    for (int k = 0; k < 4; ++k) {
      sgf[k] = *(const bf16x8*)(sg1p + k * 512 + lane * 8);
      gwf[k] = *(const bf16x8*)(gwp  + k * 512 + lane * 8);
    }
#pragma unroll
    for (int m = 0; m < 2; ++m) {
      f32x4 acc = {0.f, 0.f, 0.f, 0.f};
#pragma unroll
      for (int k = 0; k < 4; ++k)
        acc = __builtin_amdgcn_mfma_f32_16x16x32_bf16(xf[m][k], sgf[k], acc, 0, 0, 0);
#pragma unroll
      for (int r = 0; r < 4; ++r)
        Ulw[(m * 16 + lg * 4 + r) * 40 + l15] = f2bs(fmaxf(acc[r], 0.f));
    }
    f32x4 sc[2];
#pragma unroll
    for (int m = 0; m < 2; ++m) {
      f32x4 acc = {0.f, 0.f, 0.f, 0.f};
#pragma unroll
      for (int k = 0; k < 4; ++k)
        acc = __builtin_amdgcn_mfma_f32_16x16x32_bf16(xf[m][k], gwf[k], acc, 0, 0, 0);
      sc[m] = acc;
    }
    __syncthreads();  // U-writes (rows lg*4+r) visible to uf-reads (rows l15)
    bf16x8 gcf = *(const bf16x8*)(gcp + lane * 8);
#pragma unroll
    for (int m = 0; m < 2; ++m) {
      bf16x8 uf = *(const bf16x8*)(Ulw + (m * 16 + l15) * 40 + lg * 8);
      sc[m] = __builtin_amdgcn_mfma_f32_16x16x32_bf16(uf, gcf, sc[m], 0, 0, 0);
    }
    int b = tokw >> 12;
    float am = (l15 < 8 && active[b * 8 + l15] != 0) ? 0.f : -3.0e38f;
#pragma unroll
    for (int m = 0; m < 2; ++m) {
      f32x4 w4;
#pragma unroll
      for (int r = 0; r < 4; ++r) {
        float s = sc[m][r] + am;
        float mx = s;
        mx = fmaxf(mx, __shfl_xor(mx, 1));
        mx = fmaxf(mx, __shfl_xor(mx, 2));
        mx = fmaxf(mx, __shfl_xor(mx, 4));
        float p = __expf(s - mx);
        float su = p;
        su += __shfl_xor(su, 1);
        su += __shfl_xor(su, 2);
        su += __shfl_xor(su, 4);
        w4[r] = p / su;
      }
      wreg[m] = w4;
    }
  }

  // ---- expert loop: counted-vmcnt ring pipeline, no drains ----
  f32x4 acc2[2][8];
#pragma unroll
  for (int m = 0; m < 2; ++m)
#pragma unroll
    for (int o = 0; o < 8; ++o)
      acc2[m][o] = {0.f, 0.f, 0.f, 0.f};

  for (int e = 0; e < 8; ++e) {
    // wv[m] = w[token=l15 (+m*16)][e]; source lane ((l15>>2)<<4)|e, reg l15&3
    float wv[2];
    {
      int srcb = ((l15 >> 2) << 4) | e;
      int rp = l15 & 3;
#pragma unroll
      for (int m = 0; m < 2; ++m) {
        float q0 = __shfl(wreg[m][0], srcb), q1 = __shfl(wreg[m][1], srcb);
        float q2 = __shfl(wreg[m][2], srcb), q3 = __shfl(wreg[m][3], srcb);
        float lo = (rp & 1) ? q1 : q0, hi = (rp & 1) ? q3 : q2;
        wv[m] = (rp & 2) ? hi : lo;
      }
    }

#pragma unroll
    for (int ks = 0; ks < 8; ++ks) {
      const int c = e * 8 + ks;
      if (c + 2 < 64) stage(c + 2);          // issue prefetch (never drained here)
      waitv(c <= 61 ? 8 : (c == 62 ? 4 : 0)); // own chunk-c loads have landed
      __builtin_amdgcn_s_barrier();           // everyone's chunk-c loads landed

      const short* wb = &Wring[c & 3][0];
      bf16x8 Af[8], Bf[8];
#pragma unroll
      for (int i = 0; i < 8; ++i) {
        Af[i] = *(const bf16x8*)(wb + i * 512 + lane * 8);
        Bf[i] = *(const bf16x8*)(wb + 4096 + i * 512 + lane * 8);
      }

      // G1: D[hid][token] for this 32-hid chunk (2 hid-tiles x K=128)
      f32x4 a1[2][2];
#pragma unroll
      for (int m = 0; m < 2; ++m)
#pragma unroll
        for (int n = 0; n < 2; ++n) {
          f32x4 acc = {0.f, 0.f, 0.f, 0.f};
#pragma unroll
          for (int kx = 0; kx < 4; ++kx)
            acc = __builtin_amdgcn_mfma_f32_16x16x32_bf16(Af[n * 4 + kx], xf[m][kx], acc, 0, 0, 0);
          a1[m][n] = acc;
        }
      // pack: relu * wv, f32 -> packed bf16 (v_cvt_pk_bf16_f32)
      bf16x8 hB[2];
#pragma unroll
      for (int m = 0; m < 2; ++m) {
        float s = wv[m];
        union { unsigned u[4]; bf16x8 v; } hb;
        hb.u[0] = pk2(fmaxf(a1[m][0][0], 0.f) * s, fmaxf(a1[m][0][1], 0.f) * s);
        hb.u[1] = pk2(fmaxf(a1[m][0][2], 0.f) * s, fmaxf(a1[m][0][3], 0.f) * s);
        hb.u[2] = pk2(fmaxf(a1[m][1][0], 0.f) * s, fmaxf(a1[m][1][1], 0.f) * s);
        hb.u[3] = pk2(fmaxf(a1[m][1][2], 0.f) * s, fmaxf(a1[m][1][3], 0.f) * s);
        hB[m] = hb.v;
      }
      // G2: acc2[m][o] += mfma(W2frag[o], hB[m])  (D[out][token])
#pragma unroll
      for (int o = 0; o < 8; ++o)
#pragma unroll
        for (int m = 0; m < 2; ++m)
          acc2[m][o] = __builtin_amdgcn_mfma_f32_16x16x32_bf16(Bf[o], hB[m], acc2[m][o], 0, 0, 0);
    }
  }

  // ---- direct stores: lane holds out = o*16+lg*4..+3, token = l15 (+m*16) ----
#pragma unroll
  for (int m = 0; m < 2; ++m)
#pragma unroll
    for (int o = 0; o < 8; ++o)
      *(f32x4*)(out + (size_t)(tokw + m * 16 + l15) * 128 + o * 16 + lg * 4) = acc2[m][o];

  if (blockIdx.x == 0 && tid == 0) out[8388608] = 0.0f;  // aux_loss
}

extern "C" void kernel_launch(void* const* d_in, const int* in_sizes, int n_in,
                              void* d_out, int out_size, void* d_ws, size_t ws_size,
                              hipStream_t stream) {
  const float* x      = (const float*)d_in[0];
  const int*   act    = (const int*)d_in[1];
  const float* sg_w1  = (const float*)d_in[2];
  const float* sg_w2  = (const float*)d_in[3];
  const float* gate_w = (const float*)d_in[4];
  const float* exp_w1 = (const float*)d_in[5];
  const float* exp_w2 = (const float*)d_in[6];
  short* ws_s = (short*)d_ws;
  float* out = (float*)d_out;

  prep_kernel<<<2066, 256, 0, stream>>>(sg_w1, sg_w2, gate_w, exp_w1, exp_w2, ws_s);
  moe_kernel<<<512, 256, 0, stream>>>(x, act, ws_s, out);
}